// Round 11
// baseline (662.774 us; speedup 1.0000x reference)
//
#include <hip/hip_runtime.h>
#include <hip/hip_bf16.h>
#include <hip/hip_fp16.h>

#define NGRAPH 128
#define NCLS 10
#define BN_EPS 1e-5f
#define SCAN_CHUNK 1024
#define LDH 72   // padded LDS row stride in halves (144B)

typedef _Float16 h16;
typedef __attribute__((ext_vector_type(8))) _Float16 f16x8;
typedef __attribute__((ext_vector_type(4))) float f32x4;

// ---------------- CSR build ----------------

__global__ void scan1_kernel(const int* __restrict__ deg, int* __restrict__ part, int N) {
    __shared__ int sh[256];
    int base = blockIdx.x * SCAN_CHUNK + threadIdx.x * 4;
    int s = 0;
#pragma unroll
    for (int i = 0; i < 4; i++) { int idx = base + i; if (idx < N) s += deg[idx]; }
    sh[threadIdx.x] = s; __syncthreads();
    for (int off = 128; off > 0; off >>= 1) {
        if (threadIdx.x < off) sh[threadIdx.x] += sh[threadIdx.x + off];
        __syncthreads();
    }
    if (threadIdx.x == 0) part[blockIdx.x] = sh[0];
}

__global__ void scan2_kernel(int* __restrict__ part, int nblk, int* __restrict__ row_ptr, int N, int E) {
    __shared__ int sh[256];
    int v = (threadIdx.x < nblk) ? part[threadIdx.x] : 0;
    sh[threadIdx.x] = v; __syncthreads();
    for (int off = 1; off < 256; off <<= 1) {
        int t = (threadIdx.x >= off) ? sh[threadIdx.x - off] : 0;
        __syncthreads();
        sh[threadIdx.x] += t;
        __syncthreads();
    }
    if (threadIdx.x < nblk) part[threadIdx.x] = sh[threadIdx.x] - v;  // exclusive
    if (threadIdx.x == 0) row_ptr[N] = E;
}

__global__ void scan3_kernel(const int* __restrict__ deg, const int* __restrict__ part,
                             int* __restrict__ row_ptr, int* __restrict__ cursor, int N) {
    __shared__ int sh[256];
    int tbase = blockIdx.x * SCAN_CHUNK + threadIdx.x * 4;
    int vals[4]; int s = 0;
#pragma unroll
    for (int i = 0; i < 4; i++) { int idx = tbase + i; vals[i] = (idx < N) ? deg[idx] : 0; s += vals[i]; }
    sh[threadIdx.x] = s; __syncthreads();
    for (int off = 1; off < 256; off <<= 1) {
        int t = (threadIdx.x >= off) ? sh[threadIdx.x - off] : 0;
        __syncthreads();
        sh[threadIdx.x] += t;
        __syncthreads();
    }
    int run = part[blockIdx.x] + sh[threadIdx.x] - s;
#pragma unroll
    for (int i = 0; i < 4; i++) {
        int idx = tbase + i;
        if (idx < N) { row_ptr[idx] = run; cursor[idx] = run; run += vals[i]; }
    }
}

__global__ void scatter_kernel(const int* __restrict__ src, const int* __restrict__ dst,
                               int* __restrict__ cursor, int* __restrict__ col, int E) {
    int e = blockIdx.x * blockDim.x + threadIdx.x;
    if (e < E) {
        int pos = atomicAdd(&cursor[dst[e]], 1);
        col[pos] = src[e];
    }
}

// ---------------- Weight prep: transpose+convert 7 64x64 fp32 -> fp16 [j][k] ----------------
// order: 0:W2_0  1..3:W2r[0..2]  4..6:W1r[0..2]

__global__ void prep_weights_kernel(const float* __restrict__ W2_0,
                                    const float* __restrict__ W2r,
                                    const float* __restrict__ W1r,
                                    h16* __restrict__ wt) {
    int b = blockIdx.x;
    const float* src = (b == 0) ? W2_0 : (b <= 3) ? W2r + (size_t)(b - 1) * 4096
                                                  : W1r + (size_t)(b - 4) * 4096;
    h16* dst = wt + (size_t)b * 4096;
    for (int i = threadIdx.x; i < 4096; i += 256) {
        int k = i >> 6, j = i & 63;
        dst[j * 64 + k] = (h16)src[k * 64 + j];
    }
}

// ---------------- Fused: degree-count (blocks [0,eb)) + layer-0 GEMM (blocks [eb,eb+mb)) ----
// count is latency/atomic-bound with tiny traffic -> good overlap partner for the
// VALU-bound K=128 GEMM (the write-storm scatter was a bad partner: R6 110us = sum).

__global__ void __launch_bounds__(256) fused_count_gemm0_kernel(
        const int* __restrict__ dst, int* __restrict__ deg, int E, int eb,
        const float* __restrict__ X, const float* __restrict__ W,
        __half* __restrict__ Y, int N) {
    __shared__ float Xs[64 * 64];
    __shared__ float Ws[64 * 64];

    if ((int)blockIdx.x < eb) {
        int e = blockIdx.x * 256 + threadIdx.x;
        if (e < E) atomicAdd(&deg[dst[e]], 1);
        return;
    }

    const int tid = threadIdx.x;
    const int base = (blockIdx.x - eb) * 64;
    const int ti = tid >> 4;
    const int tj = tid & 15;
    float4 acc[4];
#pragma unroll
    for (int a = 0; a < 4; a++) acc[a] = make_float4(0.f, 0.f, 0.f, 0.f);

    for (int kh = 0; kh < 2; kh++) {
        {
            const float4* Wv = reinterpret_cast<const float4*>(W + kh * 64 * 64);
            float4* Wsv = reinterpret_cast<float4*>(Ws);
            for (int i = tid; i < 1024; i += 256) Wsv[i] = Wv[i];
        }
        for (int i = tid; i < 1024; i += 256) {
            int r = i & 63;
            int c4 = i >> 6;
            int n = base + r;
            float4 v = make_float4(0.f, 0.f, 0.f, 0.f);
            if (n < N) v = *reinterpret_cast<const float4*>(X + (size_t)n * 128 + kh * 64 + c4 * 4);
            Xs[(c4 * 4 + 0) * 64 + r] = v.x;
            Xs[(c4 * 4 + 1) * 64 + r] = v.y;
            Xs[(c4 * 4 + 2) * 64 + r] = v.z;
            Xs[(c4 * 4 + 3) * 64 + r] = v.w;
        }
        __syncthreads();

#pragma unroll 4
        for (int k = 0; k < 64; k++) {
            float4 xv = *reinterpret_cast<const float4*>(&Xs[k * 64 + 4 * ti]);
            float4 wv = *reinterpret_cast<const float4*>(&Ws[k * 64 + 4 * tj]);
            acc[0].x += xv.x * wv.x; acc[0].y += xv.x * wv.y; acc[0].z += xv.x * wv.z; acc[0].w += xv.x * wv.w;
            acc[1].x += xv.y * wv.x; acc[1].y += xv.y * wv.y; acc[1].z += xv.y * wv.z; acc[1].w += xv.y * wv.w;
            acc[2].x += xv.z * wv.x; acc[2].y += xv.z * wv.y; acc[2].z += xv.z * wv.z; acc[2].w += xv.z * wv.w;
            acc[3].x += xv.w * wv.x; acc[3].y += xv.w * wv.y; acc[3].z += xv.w * wv.z; acc[3].w += xv.w * wv.w;
        }
        __syncthreads();
    }

#pragma unroll
    for (int a = 0; a < 4; a++) {
        int n = base + 4 * ti + a;
        if (n < N) {
            __half2* yp = reinterpret_cast<__half2*>(Y + (size_t)n * 64 + 4 * tj);
            yp[0] = __floats2half2_rn(acc[a].x, acc[a].y);
            yp[1] = __floats2half2_rn(acc[a].z, acc[a].w);
        }
    }
}

// ---------------- Fused agg+BN+ReLU+MFMA-pair: yOut = half(relu(AGG @ W2) @ W1) ----------------
// Gather phase: wave w fills Xs rows 16w..16w+15 (dual-group fp16 gather, fp32 accum,
// BN+ReLU, fp16 into LDS) — the fp32 hA round-trip through global is eliminated.
// MFMA phase: identical to the proven gemm_pair_mfma (wave-private rows through both
// stages). yIn/yOut must be distinct buffers (ping-pong).

__global__ void __launch_bounds__(256) fused_agg_pair(
        const __half* __restrict__ yIn, const int* __restrict__ rp,
        const int* __restrict__ col,
        const float* __restrict__ gam, const float* __restrict__ bet,
        const float* __restrict__ mu, const float* __restrict__ var,
        const h16* __restrict__ Wt2, const h16* __restrict__ Wt1,
        __half* __restrict__ yOut, int N) {
    __shared__ h16 Xs[64 * LDH];
    __shared__ h16 W2s[64 * LDH];
    __shared__ h16 W1s[64 * LDH];
    const int tid = threadIdx.x;
    const int base = blockIdx.x * 64;

    // stage weights (issue early; covered by the gather phase + barrier)
#pragma unroll
    for (int it = 0; it < 2; ++it) {
        int idx = it * 256 + tid;
        int row = idx >> 3, q = idx & 7;
        *reinterpret_cast<f16x8*>(&W2s[row * LDH + q * 8]) =
            *reinterpret_cast<const f16x8*>(Wt2 + row * 64 + q * 8);
        *reinterpret_cast<f16x8*>(&W1s[row * LDH + q * 8]) =
            *reinterpret_cast<const f16x8*>(Wt1 + row * 64 + q * 8);
    }

    const int w   = tid >> 6;
    const int l   = tid & 63;
    const int grp = l >> 5;      // 0: even edges (+self), 1: odd edges
    const int fl  = l & 31;      // feature-pair index
    const int f0  = fl * 2;

    const float sc0 = gam[f0] * rsqrtf(var[f0] + BN_EPS);
    const float sh0 = bet[f0] - mu[f0] * sc0;
    const float sc1 = gam[f0 + 1] * rsqrtf(var[f0 + 1] + BN_EPS);
    const float sh1 = bet[f0 + 1] - mu[f0 + 1] * sc1;

    for (int r = 0; r < 16; ++r) {
        int node = base + 16 * w + r;
        float2 acc = make_float2(0.f, 0.f);
        if (node < N) {
            int beg = rp[node], end = rp[node + 1];
            if (grp == 0) {
                float2 f = __half22float2(*reinterpret_cast<const __half2*>(yIn + (size_t)node * 64 + f0));
                acc.x += f.x; acc.y += f.y;
            }
            int e = beg + grp;
            for (; e + 6 < end; e += 8) {
                int s0 = col[e], s1 = col[e + 2], s2 = col[e + 4], s3 = col[e + 6];
                float2 a0 = __half22float2(*reinterpret_cast<const __half2*>(yIn + (size_t)s0 * 64 + f0));
                float2 a1 = __half22float2(*reinterpret_cast<const __half2*>(yIn + (size_t)s1 * 64 + f0));
                float2 a2 = __half22float2(*reinterpret_cast<const __half2*>(yIn + (size_t)s2 * 64 + f0));
                float2 a3 = __half22float2(*reinterpret_cast<const __half2*>(yIn + (size_t)s3 * 64 + f0));
                acc.x += a0.x + a1.x + a2.x + a3.x;
                acc.y += a0.y + a1.y + a2.y + a3.y;
            }
            for (; e < end; e += 2) {
                float2 a = __half22float2(*reinterpret_cast<const __half2*>(yIn + (size_t)col[e] * 64 + f0));
                acc.x += a.x; acc.y += a.y;
            }
            acc.x += __shfl_down(acc.x, 32);
            acc.y += __shfl_down(acc.y, 32);
        }
        if (grp == 0) {
            h16 v0 = (h16)0.f, v1 = (h16)0.f;
            if (node < N) {
                v0 = (h16)fmaxf(acc.x * sc0 + sh0, 0.f);
                v1 = (h16)fmaxf(acc.y * sc1 + sh1, 0.f);
            }
            Xs[(16 * w + r) * LDH + f0]     = v0;
            Xs[(16 * w + r) * LDH + f0 + 1] = v1;
        }
    }
    __syncthreads();

    const int lr = l & 15;
    const int lk = l >> 4;

    // ---- stage 1: Z = relu(X @ W2) ----
    f16x8 a0 = *reinterpret_cast<const f16x8*>(&Xs[(16 * w + lr) * LDH + lk * 8]);
    f16x8 a1 = *reinterpret_cast<const f16x8*>(&Xs[(16 * w + lr) * LDH + 32 + lk * 8]);
    f32x4 acc1[4];
#pragma unroll
    for (int t = 0; t < 4; ++t) {
        f16x8 b0 = *reinterpret_cast<const f16x8*>(&W2s[(16 * t + lr) * LDH + lk * 8]);
        f16x8 b1 = *reinterpret_cast<const f16x8*>(&W2s[(16 * t + lr) * LDH + 32 + lk * 8]);
        f32x4 c = {0.f, 0.f, 0.f, 0.f};
        c = __builtin_amdgcn_mfma_f32_16x16x32_f16(a0, b0, c, 0, 0, 0);
        c = __builtin_amdgcn_mfma_f32_16x16x32_f16(a1, b1, c, 0, 0, 0);
        acc1[t] = c;
    }
#pragma unroll
    for (int t = 0; t < 4; ++t)
#pragma unroll
        for (int r = 0; r < 4; ++r)
            Xs[(16 * w + lk * 4 + r) * LDH + 16 * t + lr] = (h16)fmaxf(acc1[t][r], 0.f);
    __syncthreads();

    // ---- stage 2: Y = Z @ W1 ----
    f16x8 z0 = *reinterpret_cast<const f16x8*>(&Xs[(16 * w + lr) * LDH + lk * 8]);
    f16x8 z1 = *reinterpret_cast<const f16x8*>(&Xs[(16 * w + lr) * LDH + 32 + lk * 8]);
    f32x4 acc2[4];
#pragma unroll
    for (int t = 0; t < 4; ++t) {
        f16x8 b0 = *reinterpret_cast<const f16x8*>(&W1s[(16 * t + lr) * LDH + lk * 8]);
        f16x8 b1 = *reinterpret_cast<const f16x8*>(&W1s[(16 * t + lr) * LDH + 32 + lk * 8]);
        f32x4 c = {0.f, 0.f, 0.f, 0.f};
        c = __builtin_amdgcn_mfma_f32_16x16x32_f16(z0, b0, c, 0, 0, 0);
        c = __builtin_amdgcn_mfma_f32_16x16x32_f16(z1, b1, c, 0, 0, 0);
        acc2[t] = c;
    }
#pragma unroll
    for (int t = 0; t < 4; ++t)
#pragma unroll
        for (int r = 0; r < 4; ++r)
            W2s[(16 * w + lk * 4 + r) * LDH + 16 * t + lr] = (h16)acc2[t][r];
    __syncthreads();

#pragma unroll
    for (int it = 0; it < 2; ++it) {
        int idx = it * 256 + tid;
        int row = idx >> 3, q = idx & 7;
        int n = base + row;
        if (n < N)
            *reinterpret_cast<f16x8*>(reinterpret_cast<h16*>(yOut) + (size_t)n * 64 + q * 8) =
                *reinterpret_cast<const f16x8*>(&W2s[row * LDH + q * 8]);
    }
}

// ---------------- Fused agg+BN+ReLU+MFMA-last: hOut(f32) = relu(AGG @ W2_3) ----------------

__global__ void __launch_bounds__(256) fused_agg_last(
        const __half* __restrict__ yIn, const int* __restrict__ rp,
        const int* __restrict__ col,
        const float* __restrict__ gam, const float* __restrict__ bet,
        const float* __restrict__ mu, const float* __restrict__ var,
        const h16* __restrict__ Wt, float* __restrict__ hOut, int N) {
    __shared__ h16 Xs[64 * LDH];
    __shared__ h16 Ws[64 * LDH];
    __shared__ float Zf[64 * 68];
    const int tid = threadIdx.x;
    const int base = blockIdx.x * 64;

#pragma unroll
    for (int it = 0; it < 2; ++it) {
        int idx = it * 256 + tid;
        int row = idx >> 3, q = idx & 7;
        *reinterpret_cast<f16x8*>(&Ws[row * LDH + q * 8]) =
            *reinterpret_cast<const f16x8*>(Wt + row * 64 + q * 8);
    }

    const int w   = tid >> 6;
    const int l   = tid & 63;
    const int grp = l >> 5;
    const int fl  = l & 31;
    const int f0  = fl * 2;

    const float sc0 = gam[f0] * rsqrtf(var[f0] + BN_EPS);
    const float sh0 = bet[f0] - mu[f0] * sc0;
    const float sc1 = gam[f0 + 1] * rsqrtf(var[f0 + 1] + BN_EPS);
    const float sh1 = bet[f0 + 1] - mu[f0 + 1] * sc1;

    for (int r = 0; r < 16; ++r) {
        int node = base + 16 * w + r;
        float2 acc = make_float2(0.f, 0.f);
        if (node < N) {
            int beg = rp[node], end = rp[node + 1];
            if (grp == 0) {
                float2 f = __half22float2(*reinterpret_cast<const __half2*>(yIn + (size_t)node * 64 + f0));
                acc.x += f.x; acc.y += f.y;
            }
            int e = beg + grp;
            for (; e + 6 < end; e += 8) {
                int s0 = col[e], s1 = col[e + 2], s2 = col[e + 4], s3 = col[e + 6];
                float2 a0 = __half22float2(*reinterpret_cast<const __half2*>(yIn + (size_t)s0 * 64 + f0));
                float2 a1 = __half22float2(*reinterpret_cast<const __half2*>(yIn + (size_t)s1 * 64 + f0));
                float2 a2 = __half22float2(*reinterpret_cast<const __half2*>(yIn + (size_t)s2 * 64 + f0));
                float2 a3 = __half22float2(*reinterpret_cast<const __half2*>(yIn + (size_t)s3 * 64 + f0));
                acc.x += a0.x + a1.x + a2.x + a3.x;
                acc.y += a0.y + a1.y + a2.y + a3.y;
            }
            for (; e < end; e += 2) {
                float2 a = __half22float2(*reinterpret_cast<const __half2*>(yIn + (size_t)col[e] * 64 + f0));
                acc.x += a.x; acc.y += a.y;
            }
            acc.x += __shfl_down(acc.x, 32);
            acc.y += __shfl_down(acc.y, 32);
        }
        if (grp == 0) {
            h16 v0 = (h16)0.f, v1 = (h16)0.f;
            if (node < N) {
                v0 = (h16)fmaxf(acc.x * sc0 + sh0, 0.f);
                v1 = (h16)fmaxf(acc.y * sc1 + sh1, 0.f);
            }
            Xs[(16 * w + r) * LDH + f0]     = v0;
            Xs[(16 * w + r) * LDH + f0 + 1] = v1;
        }
    }
    __syncthreads();

    const int lr = l & 15;
    const int lk = l >> 4;

    f16x8 a0 = *reinterpret_cast<const f16x8*>(&Xs[(16 * w + lr) * LDH + lk * 8]);
    f16x8 a1 = *reinterpret_cast<const f16x8*>(&Xs[(16 * w + lr) * LDH + 32 + lk * 8]);
#pragma unroll
    for (int t = 0; t < 4; ++t) {
        f16x8 b0 = *reinterpret_cast<const f16x8*>(&Ws[(16 * t + lr) * LDH + lk * 8]);
        f16x8 b1 = *reinterpret_cast<const f16x8*>(&Ws[(16 * t + lr) * LDH + 32 + lk * 8]);
        f32x4 c = {0.f, 0.f, 0.f, 0.f};
        c = __builtin_amdgcn_mfma_f32_16x16x32_f16(a0, b0, c, 0, 0, 0);
        c = __builtin_amdgcn_mfma_f32_16x16x32_f16(a1, b1, c, 0, 0, 0);
#pragma unroll
        for (int r = 0; r < 4; ++r)
            Zf[(16 * w + lk * 4 + r) * 68 + 16 * t + lr] = fmaxf(c[r], 0.f);
    }
    __syncthreads();

#pragma unroll
    for (int it = 0; it < 4; ++it) {
        int idx = it * 256 + tid;
        int row = idx >> 4, q = idx & 15;
        int n = base + row;
        if (n < N)
            *reinterpret_cast<float4*>(hOut + (size_t)n * 64 + q * 4) =
                *reinterpret_cast<const float4*>(&Zf[row * 68 + q * 4]);
    }
}

// ---------------- Global mean pool, stage A: LDS-privatized partials ----------------

__global__ void __launch_bounds__(256) pool_partial_kernel(const float* __restrict__ h,
                                                           const int* __restrict__ batch,
                                                           float* __restrict__ partial,
                                                           int* __restrict__ pcnt, int N) {
    __shared__ float ls[NGRAPH * 64];
    __shared__ int lc[NGRAPH];
    for (int i = threadIdx.x; i < NGRAPH * 64; i += 256) ls[i] = 0.f;
    if (threadIdx.x < NGRAPH) lc[threadIdx.x] = 0;
    __syncthreads();
    int lane = threadIdx.x & 63;
    int gwave = blockIdx.x * 4 + (threadIdx.x >> 6);
    int nwaves = gridDim.x * 4;
#pragma unroll 4
    for (int n = gwave; n < N; n += nwaves) {
        int g = batch[n];
        atomicAdd(&ls[g * 64 + lane], h[(size_t)n * 64 + lane]);
        if (lane == 0) atomicAdd(&lc[g], 1);
    }
    __syncthreads();
    for (int i = threadIdx.x; i < NGRAPH * 64; i += 256)
        partial[(size_t)blockIdx.x * NGRAPH * 64 + i] = ls[i];
    if (threadIdx.x < NGRAPH) pcnt[blockIdx.x * NGRAPH + threadIdx.x] = lc[threadIdx.x];
}

// ---------------- Partial-reduce + MLP head + log_softmax (block per graph) ----------------

__global__ void head_kernel(const float* __restrict__ partial, const int* __restrict__ pcnt, int P,
                            const float* __restrict__ lin1, const float* __restrict__ lin2,
                            const float* __restrict__ b2, float* __restrict__ out) {
    int g = blockIdx.x;
    int j = threadIdx.x;
    __shared__ float p[64];
    __shared__ float z1[64];
    __shared__ float z2[NCLS];
    __shared__ int csh[64];
    float s = 0.f;
    for (int b = 0; b < P; b++) s += partial[(size_t)b * NGRAPH * 64 + g * 64 + j];
    int c = 0;
    for (int b = j; b < P; b += 64) c += pcnt[b * NGRAPH + g];
    csh[j] = c; __syncthreads();
    if (j == 0) { int t = 0; for (int k = 0; k < 64; k++) t += csh[k]; csh[0] = t; }
    __syncthreads();
    float cnt = fmaxf((float)csh[0], 1.f);
    p[j] = s / cnt;
    __syncthreads();
    float a = 0.f;
#pragma unroll
    for (int k = 0; k < 64; k++) a += p[k] * lin1[k * 64 + j];
    z1[j] = fmaxf(a, 0.f);
    __syncthreads();
    if (j < NCLS) {
        float t = b2[j];
#pragma unroll
        for (int k = 0; k < 64; k++) t += z1[k] * lin2[k * NCLS + j];
        z2[j] = t;
    }
    __syncthreads();
    if (j < NCLS) {
        float mx = -1e30f;
#pragma unroll
        for (int c2 = 0; c2 < NCLS; c2++) mx = fmaxf(mx, z2[c2]);
        float se = 0.f;
#pragma unroll
        for (int c2 = 0; c2 < NCLS; c2++) se += expf(z2[c2] - mx);
        out[g * NCLS + j] = z2[j] - mx - logf(se);
    }
}

// ---------------- launch ----------------

extern "C" void kernel_launch(void* const* d_in, const int* in_sizes, int n_in,
                              void* d_out, int out_size, void* d_ws, size_t ws_size,
                              hipStream_t stream) {
    const float* x     = (const float*)d_in[0];
    const int*   ei    = (const int*)d_in[1];
    const int*   batch = (const int*)d_in[2];
    const float* W1_0  = (const float*)d_in[3];
    const float* g0    = (const float*)d_in[4];
    const float* b0    = (const float*)d_in[5];
    const float* m0    = (const float*)d_in[6];
    const float* v0    = (const float*)d_in[7];
    const float* W2_0  = (const float*)d_in[8];
    const float* W1r   = (const float*)d_in[9];
    const float* gr    = (const float*)d_in[10];
    const float* br    = (const float*)d_in[11];
    const float* mr    = (const float*)d_in[12];
    const float* vr    = (const float*)d_in[13];
    const float* W2r   = (const float*)d_in[14];
    const float* lin1  = (const float*)d_in[15];
    const float* lin2  = (const float*)d_in[16];
    const float* b2    = (const float*)d_in[17];

    const int N = in_sizes[0] / 128;   // 100000
    const int E = in_sizes[1] / 2;     // 1000000
    const int* src = ei;
    const int* dst = ei + E;

    // ---- workspace carve (256B aligned) ----
    char* p = (char*)d_ws;
    auto alloc = [&](size_t bytes) -> char* {
        char* r = p;
        p += (bytes + 255) & ~(size_t)255;
        return r;
    };
    int*    deg     = (int*)alloc((size_t)N * 4);
    int*    row_ptr = (int*)alloc((size_t)(N + 1) * 4);
    int*    cursor  = (int*)alloc((size_t)N * 4);
    int*    col     = (int*)alloc((size_t)E * 4);
    int*    part    = (int*)alloc(256 * 4);
    float*  hA      = (float*)alloc((size_t)N * 64 * 4);
    __half* yA      = (__half*)alloc((size_t)N * 64 * 2);
    __half* yB      = (__half*)alloc((size_t)N * 64 * 2);
    h16*    wt      = (h16*)alloc((size_t)7 * 4096 * 2);
    size_t used = (size_t)(p - (char*)d_ws);
    size_t per_block = ((size_t)NGRAPH * 64 * 4) + ((size_t)NGRAPH * 4) + 512;
    size_t remain = (ws_size > used) ? (ws_size - used) : 0;
    int P = (int)(remain / per_block);
    if (P > 256) P = 256;
    if (P < 1) P = 1;
    float* partial = (float*)alloc((size_t)P * NGRAPH * 64 * 4);
    int*   pcnt    = (int*)alloc((size_t)P * NGRAPH * 4);
    (void)n_in; (void)out_size;

    hipMemsetAsync(deg, 0, (size_t)N * 4, stream);

    // ---- weight prep; fused degree-count || layer-0 GEMM; scans; scatter ----
    prep_weights_kernel<<<7, 256, 0, stream>>>(W2_0, W2r, W1r, wt);
    int eb = (E + 255) / 256;
    int mb = (N + 63) / 64;
    fused_count_gemm0_kernel<<<eb + mb, 256, 0, stream>>>(dst, deg, E, eb, x, W1_0, yA, N);
    int nblk = (N + SCAN_CHUNK - 1) / SCAN_CHUNK;
    scan1_kernel<<<nblk, 256, 0, stream>>>(deg, part, N);
    scan2_kernel<<<1, 256, 0, stream>>>(part, nblk, row_ptr, N, E);
    scan3_kernel<<<nblk, 256, 0, stream>>>(deg, part, row_ptr, cursor, N);
    scatter_kernel<<<eb, 256, 0, stream>>>(src, dst, cursor, col, E);

    // ---- fused agg+BN+ReLU+pair chain (ping-pong yA/yB) ----
    fused_agg_pair<<<mb, 256, 0, stream>>>(yA, row_ptr, col, g0, b0, m0, v0,
                                           wt + 0 * 4096, wt + 4 * 4096, yB, N);
    fused_agg_pair<<<mb, 256, 0, stream>>>(yB, row_ptr, col, gr, br, mr, vr,
                                           wt + 1 * 4096, wt + 5 * 4096, yA, N);
    fused_agg_pair<<<mb, 256, 0, stream>>>(yA, row_ptr, col, gr + 64, br + 64, mr + 64, vr + 64,
                                           wt + 2 * 4096, wt + 6 * 4096, yB, N);
    fused_agg_last<<<mb, 256, 0, stream>>>(yB, row_ptr, col, gr + 128, br + 128, mr + 128, vr + 128,
                                           wt + 3 * 4096, hA, N);

    // ---- pool (LDS-privatized partials) + head ----
    pool_partial_kernel<<<P, 256, 0, stream>>>(hA, batch, partial, pcnt, N);
    head_kernel<<<NGRAPH, 64, 0, stream>>>(partial, pcnt, P, lin1, lin2, b2, (float*)d_out);
}

// Round 12
// 596.248 us; speedup vs baseline: 1.1116x; 1.1116x over previous
//
#include <hip/hip_runtime.h>
#include <hip/hip_bf16.h>
#include <hip/hip_fp16.h>

#define NGRAPH 128
#define NCLS 10
#define BN_EPS 1e-5f
#define SCAN_CHUNK 1024
#define LDH 72   // padded LDS row stride in halves (144B)

typedef _Float16 h16;
typedef __attribute__((ext_vector_type(8))) _Float16 f16x8;
typedef __attribute__((ext_vector_type(4))) float f32x4;

// ---------------- CSR build ----------------

__global__ void count_kernel(const int* __restrict__ dst, int* __restrict__ deg, int E) {
    int e = blockIdx.x * blockDim.x + threadIdx.x;
    if (e < E) atomicAdd(&deg[dst[e]], 1);
}

__global__ void scan1_kernel(const int* __restrict__ deg, int* __restrict__ part, int N) {
    __shared__ int sh[256];
    int base = blockIdx.x * SCAN_CHUNK + threadIdx.x * 4;
    int s = 0;
#pragma unroll
    for (int i = 0; i < 4; i++) { int idx = base + i; if (idx < N) s += deg[idx]; }
    sh[threadIdx.x] = s; __syncthreads();
    for (int off = 128; off > 0; off >>= 1) {
        if (threadIdx.x < off) sh[threadIdx.x] += sh[threadIdx.x + off];
        __syncthreads();
    }
    if (threadIdx.x == 0) part[blockIdx.x] = sh[0];
}

__global__ void scan2_kernel(int* __restrict__ part, int nblk, int* __restrict__ row_ptr, int N, int E) {
    __shared__ int sh[256];
    int v = (threadIdx.x < nblk) ? part[threadIdx.x] : 0;
    sh[threadIdx.x] = v; __syncthreads();
    for (int off = 1; off < 256; off <<= 1) {
        int t = (threadIdx.x >= off) ? sh[threadIdx.x - off] : 0;
        __syncthreads();
        sh[threadIdx.x] += t;
        __syncthreads();
    }
    if (threadIdx.x < nblk) part[threadIdx.x] = sh[threadIdx.x] - v;  // exclusive
    if (threadIdx.x == 0) row_ptr[N] = E;
}

__global__ void scan3_kernel(const int* __restrict__ deg, const int* __restrict__ part,
                             int* __restrict__ row_ptr, int* __restrict__ cursor, int N) {
    __shared__ int sh[256];
    int tbase = blockIdx.x * SCAN_CHUNK + threadIdx.x * 4;
    int vals[4]; int s = 0;
#pragma unroll
    for (int i = 0; i < 4; i++) { int idx = tbase + i; vals[i] = (idx < N) ? deg[idx] : 0; s += vals[i]; }
    sh[threadIdx.x] = s; __syncthreads();
    for (int off = 1; off < 256; off <<= 1) {
        int t = (threadIdx.x >= off) ? sh[threadIdx.x - off] : 0;
        __syncthreads();
        sh[threadIdx.x] += t;
        __syncthreads();
    }
    int run = part[blockIdx.x] + sh[threadIdx.x] - s;
#pragma unroll
    for (int i = 0; i < 4; i++) {
        int idx = tbase + i;
        if (idx < N) { row_ptr[idx] = run; cursor[idx] = run; run += vals[i]; }
    }
}

// ---------------- Weight prep: transpose+convert 7 64x64 fp32 -> fp16 [j][k] ----------------
// order: 0:W2_0  1..3:W2r[0..2]  4..6:W1r[0..2]

__global__ void prep_weights_kernel(const float* __restrict__ W2_0,
                                    const float* __restrict__ W2r,
                                    const float* __restrict__ W1r,
                                    h16* __restrict__ wt) {
    int b = blockIdx.x;
    const float* src = (b == 0) ? W2_0 : (b <= 3) ? W2r + (size_t)(b - 1) * 4096
                                                  : W1r + (size_t)(b - 4) * 4096;
    h16* dst = wt + (size_t)b * 4096;
    for (int i = threadIdx.x; i < 4096; i += 256) {
        int k = i >> 6, j = i & 63;
        dst[j * 64 + k] = (h16)src[k * 64 + j];
    }
}

// ---------------- Fused: scatter (blocks [0,eb)) + layer-0 GEMM fp32 (blocks [eb,eb+mb)) ----
// (R10-proven pairing: scatter's 70MB write storm overlaps the VALU-ish K=128 GEMM.)

__global__ void __launch_bounds__(256) fused_scatter_gemm0_kernel(
        const int* __restrict__ src, const int* __restrict__ dst,
        int* __restrict__ cursor, int* __restrict__ col, int E, int eb,
        const float* __restrict__ X, const float* __restrict__ W,
        __half* __restrict__ Y, int N) {
    __shared__ float Xs[64 * 64];
    __shared__ float Ws[64 * 64];

    if ((int)blockIdx.x < eb) {
        int e = blockIdx.x * 256 + threadIdx.x;
        if (e < E) {
            int pos = atomicAdd(&cursor[dst[e]], 1);
            col[pos] = src[e];
        }
        return;
    }

    const int tid = threadIdx.x;
    const int base = (blockIdx.x - eb) * 64;
    const int ti = tid >> 4;
    const int tj = tid & 15;
    float4 acc[4];
#pragma unroll
    for (int a = 0; a < 4; a++) acc[a] = make_float4(0.f, 0.f, 0.f, 0.f);

    for (int kh = 0; kh < 2; kh++) {
        {
            const float4* Wv = reinterpret_cast<const float4*>(W + kh * 64 * 64);
            float4* Wsv = reinterpret_cast<float4*>(Ws);
            for (int i = tid; i < 1024; i += 256) Wsv[i] = Wv[i];
        }
        for (int i = tid; i < 1024; i += 256) {
            int r = i & 63;
            int c4 = i >> 6;
            int n = base + r;
            float4 v = make_float4(0.f, 0.f, 0.f, 0.f);
            if (n < N) v = *reinterpret_cast<const float4*>(X + (size_t)n * 128 + kh * 64 + c4 * 4);
            Xs[(c4 * 4 + 0) * 64 + r] = v.x;
            Xs[(c4 * 4 + 1) * 64 + r] = v.y;
            Xs[(c4 * 4 + 2) * 64 + r] = v.z;
            Xs[(c4 * 4 + 3) * 64 + r] = v.w;
        }
        __syncthreads();

#pragma unroll 4
        for (int k = 0; k < 64; k++) {
            float4 xv = *reinterpret_cast<const float4*>(&Xs[k * 64 + 4 * ti]);
            float4 wv = *reinterpret_cast<const float4*>(&Ws[k * 64 + 4 * tj]);
            acc[0].x += xv.x * wv.x; acc[0].y += xv.x * wv.y; acc[0].z += xv.x * wv.z; acc[0].w += xv.x * wv.w;
            acc[1].x += xv.y * wv.x; acc[1].y += xv.y * wv.y; acc[1].z += xv.y * wv.z; acc[1].w += xv.y * wv.w;
            acc[2].x += xv.z * wv.x; acc[2].y += xv.z * wv.y; acc[2].z += xv.z * wv.z; acc[2].w += xv.z * wv.w;
            acc[3].x += xv.w * wv.x; acc[3].y += xv.w * wv.y; acc[3].z += xv.w * wv.z; acc[3].w += xv.w * wv.w;
        }
        __syncthreads();
    }

#pragma unroll
    for (int a = 0; a < 4; a++) {
        int n = base + 4 * ti + a;
        if (n < N) {
            __half2* yp = reinterpret_cast<__half2*>(Y + (size_t)n * 64 + 4 * tj);
            yp[0] = __floats2half2_rn(acc[a].x, acc[a].y);
            yp[1] = __floats2half2_rn(acc[a].z, acc[a].w);
        }
    }
}

// ---------------- Aggregation (pull, CSR, fp16, 4-edge groups) + BN + ReLU -> fp16 ----------------
// Wave per node. Lane l: edge-group eg=l>>4 (4 groups), feature-quad fq=l&15.
// One VMEM inst covers 4 rows (16 lanes x 8B each); unroll 2 -> 16 rows in flight/wave.
// Cross-group combine: 2 shfl_xor. Full occupancy (no LDS, low VGPR).

__global__ void agg_bn_relu16(const __half* __restrict__ yIn, const int* __restrict__ rp,
                              const int* __restrict__ col,
                              const float* __restrict__ gam, const float* __restrict__ bet,
                              const float* __restrict__ mu, const float* __restrict__ var,
                              __half* __restrict__ yOut, int N) {
    int wid = (blockIdx.x * blockDim.x + threadIdx.x) >> 6;
    int l = threadIdx.x & 63;
    if (wid >= N) return;
    int eg = l >> 4;     // edge group 0..3
    int fq = l & 15;     // feature quad: features 4fq..4fq+3
    int beg = rp[wid], end = rp[wid + 1];

    float a0 = 0.f, a1 = 0.f, a2 = 0.f, a3 = 0.f;
    const h16* yh = reinterpret_cast<const h16*>(yIn);

    auto accum = [&](int node) {
        uint2 u = *reinterpret_cast<const uint2*>(yh + (size_t)node * 64 + fq * 4);
        __half2 h0 = *reinterpret_cast<__half2*>(&u.x);
        __half2 h1 = *reinterpret_cast<__half2*>(&u.y);
        float2 f0 = __half22float2(h0);
        float2 f1 = __half22float2(h1);
        a0 += f0.x; a1 += f0.y; a2 += f1.x; a3 += f1.y;
    };

    if (eg == 0) accum(wid);   // self row

    int e = beg + eg;
    for (; e + 4 < end; e += 8) {   // 2 rows per group per iter -> 8 rows in flight
        int s0 = col[e], s1 = col[e + 4];
        uint2 u0 = *reinterpret_cast<const uint2*>(yh + (size_t)s0 * 64 + fq * 4);
        uint2 u1 = *reinterpret_cast<const uint2*>(yh + (size_t)s1 * 64 + fq * 4);
        __half2 p0 = *reinterpret_cast<__half2*>(&u0.x);
        __half2 p1 = *reinterpret_cast<__half2*>(&u0.y);
        __half2 q0 = *reinterpret_cast<__half2*>(&u1.x);
        __half2 q1 = *reinterpret_cast<__half2*>(&u1.y);
        float2 fp0 = __half22float2(p0), fp1 = __half22float2(p1);
        float2 fq0 = __half22float2(q0), fq1 = __half22float2(q1);
        a0 += fp0.x + fq0.x; a1 += fp0.y + fq0.y;
        a2 += fp1.x + fq1.x; a3 += fp1.y + fq1.y;
    }
    if (e < end) accum(col[e]);

    // combine the 4 edge-groups (butterfly over lane bits 4,5)
    a0 += __shfl_xor(a0, 16); a1 += __shfl_xor(a1, 16);
    a2 += __shfl_xor(a2, 16); a3 += __shfl_xor(a3, 16);
    a0 += __shfl_xor(a0, 32); a1 += __shfl_xor(a1, 32);
    a2 += __shfl_xor(a2, 32); a3 += __shfl_xor(a3, 32);

    if (eg == 0) {
        float4 g4 = *reinterpret_cast<const float4*>(gam + fq * 4);
        float4 v4 = *reinterpret_cast<const float4*>(var + fq * 4);
        float4 m4 = *reinterpret_cast<const float4*>(mu + fq * 4);
        float4 b4 = *reinterpret_cast<const float4*>(bet + fq * 4);
        float s0 = g4.x * rsqrtf(v4.x + BN_EPS);
        float s1 = g4.y * rsqrtf(v4.y + BN_EPS);
        float s2 = g4.z * rsqrtf(v4.z + BN_EPS);
        float s3 = g4.w * rsqrtf(v4.w + BN_EPS);
        float o0 = fmaxf(a0 * s0 + (b4.x - m4.x * s0), 0.f);
        float o1 = fmaxf(a1 * s1 + (b4.y - m4.y * s1), 0.f);
        float o2 = fmaxf(a2 * s2 + (b4.z - m4.z * s2), 0.f);
        float o3 = fmaxf(a3 * s3 + (b4.w - m4.w * s3), 0.f);
        __half2 h0 = __floats2half2_rn(o0, o1);
        __half2 h1 = __floats2half2_rn(o2, o3);
        uint2 u;
        u.x = *reinterpret_cast<unsigned*>(&h0);
        u.y = *reinterpret_cast<unsigned*>(&h1);
        *reinterpret_cast<uint2*>(reinterpret_cast<h16*>(yOut) + (size_t)wid * 64 + fq * 4) = u;
    }
}

// ---------------- MFMA GEMM pair (fp16 in): Y16 = half( relu(H16 @ W2) @ W1 ) ----------------

__global__ void __launch_bounds__(256) gemm_pair_mfma(const __half* __restrict__ H,
                                                      const h16* __restrict__ Wt2,
                                                      const h16* __restrict__ Wt1,
                                                      __half* __restrict__ Y, int N) {
    __shared__ h16 Xs[64 * LDH];
    __shared__ h16 W2s[64 * LDH];
    __shared__ h16 W1s[64 * LDH];
    const int tid = threadIdx.x;
    const int base = blockIdx.x * 64;
    const h16* Hh = reinterpret_cast<const h16*>(H);

    // stage X (fp16 direct) + weights
#pragma unroll
    for (int it = 0; it < 2; ++it) {
        int idx = it * 256 + tid;
        int row = idx >> 3, q = idx & 7;
        int n = base + row;
        f16x8 v = {(h16)0.f, (h16)0.f, (h16)0.f, (h16)0.f, (h16)0.f, (h16)0.f, (h16)0.f, (h16)0.f};
        if (n < N) v = *reinterpret_cast<const f16x8*>(Hh + (size_t)n * 64 + q * 8);
        *reinterpret_cast<f16x8*>(&Xs[row * LDH + q * 8]) = v;
        *reinterpret_cast<f16x8*>(&W2s[row * LDH + q * 8]) =
            *reinterpret_cast<const f16x8*>(Wt2 + row * 64 + q * 8);
        *reinterpret_cast<f16x8*>(&W1s[row * LDH + q * 8]) =
            *reinterpret_cast<const f16x8*>(Wt1 + row * 64 + q * 8);
    }
    __syncthreads();

    const int w  = tid >> 6;
    const int l  = tid & 63;
    const int lr = l & 15;
    const int lk = l >> 4;

    // ---- stage 1: Z = relu(X @ W2) ----
    f16x8 a0 = *reinterpret_cast<const f16x8*>(&Xs[(16 * w + lr) * LDH + lk * 8]);
    f16x8 a1 = *reinterpret_cast<const f16x8*>(&Xs[(16 * w + lr) * LDH + 32 + lk * 8]);
    f32x4 acc1[4];
#pragma unroll
    for (int t = 0; t < 4; ++t) {
        f16x8 b0 = *reinterpret_cast<const f16x8*>(&W2s[(16 * t + lr) * LDH + lk * 8]);
        f16x8 b1 = *reinterpret_cast<const f16x8*>(&W2s[(16 * t + lr) * LDH + 32 + lk * 8]);
        f32x4 c = {0.f, 0.f, 0.f, 0.f};
        c = __builtin_amdgcn_mfma_f32_16x16x32_f16(a0, b0, c, 0, 0, 0);
        c = __builtin_amdgcn_mfma_f32_16x16x32_f16(a1, b1, c, 0, 0, 0);
        acc1[t] = c;
    }
#pragma unroll
    for (int t = 0; t < 4; ++t)
#pragma unroll
        for (int r = 0; r < 4; ++r)
            Xs[(16 * w + lk * 4 + r) * LDH + 16 * t + lr] = (h16)fmaxf(acc1[t][r], 0.f);
    __syncthreads();

    // ---- stage 2: Y = Z @ W1 ----
    f16x8 z0 = *reinterpret_cast<const f16x8*>(&Xs[(16 * w + lr) * LDH + lk * 8]);
    f16x8 z1 = *reinterpret_cast<const f16x8*>(&Xs[(16 * w + lr) * LDH + 32 + lk * 8]);
    f32x4 acc2[4];
#pragma unroll
    for (int t = 0; t < 4; ++t) {
        f16x8 b0 = *reinterpret_cast<const f16x8*>(&W1s[(16 * t + lr) * LDH + lk * 8]);
        f16x8 b1 = *reinterpret_cast<const f16x8*>(&W1s[(16 * t + lr) * LDH + 32 + lk * 8]);
        f32x4 c = {0.f, 0.f, 0.f, 0.f};
        c = __builtin_amdgcn_mfma_f32_16x16x32_f16(z0, b0, c, 0, 0, 0);
        c = __builtin_amdgcn_mfma_f32_16x16x32_f16(z1, b1, c, 0, 0, 0);
        acc2[t] = c;
    }
#pragma unroll
    for (int t = 0; t < 4; ++t)
#pragma unroll
        for (int r = 0; r < 4; ++r)
            W2s[(16 * w + lk * 4 + r) * LDH + 16 * t + lr] = (h16)acc2[t][r];
    __syncthreads();

#pragma unroll
    for (int it = 0; it < 2; ++it) {
        int idx = it * 256 + tid;
        int row = idx >> 3, q = idx & 7;
        int n = base + row;
        if (n < N)
            *reinterpret_cast<f16x8*>(reinterpret_cast<h16*>(Y) + (size_t)n * 64 + q * 8) =
                *reinterpret_cast<const f16x8*>(&W2s[row * LDH + q * 8]);
    }
}

// ---------------- MFMA last GEMM (fp16 in): hOut(f32) = relu(H16 @ W2_3) ----------------

__global__ void __launch_bounds__(256) gemm_last_mfma(const __half* __restrict__ H,
                                                      const h16* __restrict__ Wt,
                                                      float* __restrict__ hOut, int N) {
    __shared__ h16 Xs[64 * LDH];
    __shared__ h16 Ws[64 * LDH];
    __shared__ float Zf[64 * 68];
    const int tid = threadIdx.x;
    const int base = blockIdx.x * 64;
    const h16* Hh = reinterpret_cast<const h16*>(H);

#pragma unroll
    for (int it = 0; it < 2; ++it) {
        int idx = it * 256 + tid;
        int row = idx >> 3, q = idx & 7;
        int n = base + row;
        f16x8 v = {(h16)0.f, (h16)0.f, (h16)0.f, (h16)0.f, (h16)0.f, (h16)0.f, (h16)0.f, (h16)0.f};
        if (n < N) v = *reinterpret_cast<const f16x8*>(Hh + (size_t)n * 64 + q * 8);
        *reinterpret_cast<f16x8*>(&Xs[row * LDH + q * 8]) = v;
        *reinterpret_cast<f16x8*>(&Ws[row * LDH + q * 8]) =
            *reinterpret_cast<const f16x8*>(Wt + row * 64 + q * 8);
    }
    __syncthreads();

    const int w  = tid >> 6;
    const int l  = tid & 63;
    const int lr = l & 15;
    const int lk = l >> 4;

    f16x8 a0 = *reinterpret_cast<const f16x8*>(&Xs[(16 * w + lr) * LDH + lk * 8]);
    f16x8 a1 = *reinterpret_cast<const f16x8*>(&Xs[(16 * w + lr) * LDH + 32 + lk * 8]);
#pragma unroll
    for (int t = 0; t < 4; ++t) {
        f16x8 b0 = *reinterpret_cast<const f16x8*>(&Ws[(16 * t + lr) * LDH + lk * 8]);
        f16x8 b1 = *reinterpret_cast<const f16x8*>(&Ws[(16 * t + lr) * LDH + 32 + lk * 8]);
        f32x4 c = {0.f, 0.f, 0.f, 0.f};
        c = __builtin_amdgcn_mfma_f32_16x16x32_f16(a0, b0, c, 0, 0, 0);
        c = __builtin_amdgcn_mfma_f32_16x16x32_f16(a1, b1, c, 0, 0, 0);
#pragma unroll
        for (int r = 0; r < 4; ++r)
            Zf[(16 * w + lk * 4 + r) * 68 + 16 * t + lr] = fmaxf(c[r], 0.f);
    }
    __syncthreads();

#pragma unroll
    for (int it = 0; it < 4; ++it) {
        int idx = it * 256 + tid;
        int row = idx >> 4, q = idx & 15;
        int n = base + row;
        if (n < N)
            *reinterpret_cast<float4*>(hOut + (size_t)n * 64 + q * 4) =
                *reinterpret_cast<const float4*>(&Zf[row * 68 + q * 4]);
    }
}

// ---------------- Global mean pool, stage A: LDS-privatized partials ----------------

__global__ void __launch_bounds__(256) pool_partial_kernel(const float* __restrict__ h,
                                                           const int* __restrict__ batch,
                                                           float* __restrict__ partial,
                                                           int* __restrict__ pcnt, int N) {
    __shared__ float ls[NGRAPH * 64];
    __shared__ int lc[NGRAPH];
    for (int i = threadIdx.x; i < NGRAPH * 64; i += 256) ls[i] = 0.f;
    if (threadIdx.x < NGRAPH) lc[threadIdx.x] = 0;
    __syncthreads();
    int lane = threadIdx.x & 63;
    int gwave = blockIdx.x * 4 + (threadIdx.x >> 6);
    int nwaves = gridDim.x * 4;
#pragma unroll 4
    for (int n = gwave; n < N; n += nwaves) {
        int g = batch[n];
        atomicAdd(&ls[g * 64 + lane], h[(size_t)n * 64 + lane]);
        if (lane == 0) atomicAdd(&lc[g], 1);
    }
    __syncthreads();
    for (int i = threadIdx.x; i < NGRAPH * 64; i += 256)
        partial[(size_t)blockIdx.x * NGRAPH * 64 + i] = ls[i];
    if (threadIdx.x < NGRAPH) pcnt[blockIdx.x * NGRAPH + threadIdx.x] = lc[threadIdx.x];
}

// ---------------- Partial-reduce + MLP head + log_softmax (block per graph) ----------------

__global__ void head_kernel(const float* __restrict__ partial, const int* __restrict__ pcnt, int P,
                            const float* __restrict__ lin1, const float* __restrict__ lin2,
                            const float* __restrict__ b2, float* __restrict__ out) {
    int g = blockIdx.x;
    int j = threadIdx.x;
    __shared__ float p[64];
    __shared__ float z1[64];
    __shared__ float z2[NCLS];
    __shared__ int csh[64];
    float s = 0.f;
    for (int b = 0; b < P; b++) s += partial[(size_t)b * NGRAPH * 64 + g * 64 + j];
    int c = 0;
    for (int b = j; b < P; b += 64) c += pcnt[b * NGRAPH + g];
    csh[j] = c; __syncthreads();
    if (j == 0) { int t = 0; for (int k = 0; k < 64; k++) t += csh[k]; csh[0] = t; }
    __syncthreads();
    float cnt = fmaxf((float)csh[0], 1.f);
    p[j] = s / cnt;
    __syncthreads();
    float a = 0.f;
#pragma unroll
    for (int k = 0; k < 64; k++) a += p[k] * lin1[k * 64 + j];
    z1[j] = fmaxf(a, 0.f);
    __syncthreads();
    if (j < NCLS) {
        float t = b2[j];
#pragma unroll
        for (int k = 0; k < 64; k++) t += z1[k] * lin2[k * NCLS + j];
        z2[j] = t;
    }
    __syncthreads();
    if (j < NCLS) {
        float mx = -1e30f;
#pragma unroll
        for (int c2 = 0; c2 < NCLS; c2++) mx = fmaxf(mx, z2[c2]);
        float se = 0.f;
#pragma unroll
        for (int c2 = 0; c2 < NCLS; c2++) se += expf(z2[c2] - mx);
        out[g * NCLS + j] = z2[j] - mx - logf(se);
    }
}

// ---------------- launch ----------------

extern "C" void kernel_launch(void* const* d_in, const int* in_sizes, int n_in,
                              void* d_out, int out_size, void* d_ws, size_t ws_size,
                              hipStream_t stream) {
    const float* x     = (const float*)d_in[0];
    const int*   ei    = (const int*)d_in[1];
    const int*   batch = (const int*)d_in[2];
    const float* W1_0  = (const float*)d_in[3];
    const float* g0    = (const float*)d_in[4];
    const float* b0    = (const float*)d_in[5];
    const float* m0    = (const float*)d_in[6];
    const float* v0    = (const float*)d_in[7];
    const float* W2_0  = (const float*)d_in[8];
    const float* W1r   = (const float*)d_in[9];
    const float* gr    = (const float*)d_in[10];
    const float* br    = (const float*)d_in[11];
    const float* mr    = (const float*)d_in[12];
    const float* vr    = (const float*)d_in[13];
    const float* W2r   = (const float*)d_in[14];
    const float* lin1  = (const float*)d_in[15];
    const float* lin2  = (const float*)d_in[16];
    const float* b2    = (const float*)d_in[17];

    const int N = in_sizes[0] / 128;   // 100000
    const int E = in_sizes[1] / 2;     // 1000000
    const int* src = ei;
    const int* dst = ei + E;

    // ---- workspace carve (256B aligned) ----
    char* p = (char*)d_ws;
    auto alloc = [&](size_t bytes) -> char* {
        char* r = p;
        p += (bytes + 255) & ~(size_t)255;
        return r;
    };
    int*    deg     = (int*)alloc((size_t)N * 4);
    int*    row_ptr = (int*)alloc((size_t)(N + 1) * 4);
    int*    cursor  = (int*)alloc((size_t)N * 4);
    int*    col     = (int*)alloc((size_t)E * 4);
    int*    part    = (int*)alloc(256 * 4);
    float*  hA      = (float*)alloc((size_t)N * 64 * 4);
    __half* yA      = (__half*)alloc((size_t)N * 64 * 2);
    __half* yB      = (__half*)alloc((size_t)N * 64 * 2);
    h16*    wt      = (h16*)alloc((size_t)7 * 4096 * 2);
    size_t used = (size_t)(p - (char*)d_ws);
    size_t per_block = ((size_t)NGRAPH * 64 * 4) + ((size_t)NGRAPH * 4) + 512;
    size_t remain = (ws_size > used) ? (ws_size - used) : 0;
    int P = (int)(remain / per_block);
    if (P > 256) P = 256;
    if (P < 1) P = 1;
    float* partial = (float*)alloc((size_t)P * NGRAPH * 64 * 4);
    int*   pcnt    = (int*)alloc((size_t)P * NGRAPH * 4);
    (void)n_in; (void)out_size;

    hipMemsetAsync(deg, 0, (size_t)N * 4, stream);

    // ---- weight prep + CSR build ----
    prep_weights_kernel<<<7, 256, 0, stream>>>(W2_0, W2r, W1r, wt);
    int eb = (E + 255) / 256;
    count_kernel<<<eb, 256, 0, stream>>>(dst, deg, E);
    int nblk = (N + SCAN_CHUNK - 1) / SCAN_CHUNK;
    scan1_kernel<<<nblk, 256, 0, stream>>>(deg, part, N);
    scan2_kernel<<<1, 256, 0, stream>>>(part, nblk, row_ptr, N, E);
    scan3_kernel<<<nblk, 256, 0, stream>>>(deg, part, row_ptr, cursor, N);

    int mb = (N + 63) / 64;
    int ab = (N * 64 + 255) / 256;

    // ---- fused: CSR scatter || layer-0 GEMM (fp16 out -> yA) ----
    fused_scatter_gemm0_kernel<<<eb + mb, 256, 0, stream>>>(src, dst, cursor, col, E, eb,
                                                            x, W1_0, yA, N);

    // ---- layer chain, all fp16 (ping-pong yA/yB) ----
    agg_bn_relu16<<<ab, 256, 0, stream>>>(yA, row_ptr, col, g0, b0, m0, v0, yB, N);
    gemm_pair_mfma<<<mb, 256, 0, stream>>>(yB, wt + 0 * 4096, wt + 4 * 4096, yA, N);

    agg_bn_relu16<<<ab, 256, 0, stream>>>(yA, row_ptr, col, gr, br, mr, vr, yB, N);
    gemm_pair_mfma<<<mb, 256, 0, stream>>>(yB, wt + 1 * 4096, wt + 5 * 4096, yA, N);

    agg_bn_relu16<<<ab, 256, 0, stream>>>(yA, row_ptr, col, gr + 64, br + 64, mr + 64, vr + 64, yB, N);
    gemm_pair_mfma<<<mb, 256, 0, stream>>>(yB, wt + 2 * 4096, wt + 6 * 4096, yA, N);

    agg_bn_relu16<<<ab, 256, 0, stream>>>(yA, row_ptr, col, gr + 128, br + 128, mr + 128, vr + 128, yB, N);
    gemm_last_mfma<<<mb, 256, 0, stream>>>(yB, wt + 3 * 4096, hA, N);

    // ---- pool (LDS-privatized partials) + head ----
    pool_partial_kernel<<<P, 256, 0, stream>>>(hA, batch, partial, pcnt, N);
    head_kernel<<<NGRAPH, 64, 0, stream>>>(partial, pcnt, P, lin1, lin2, b2, (float*)d_out);
}